// Round 6
// baseline (109.578 us; speedup 1.0000x reference)
//
#include <hip/hip_runtime.h>
#include <hip/hip_fp16.h>
#include <math.h>

// WaveNet collapsed to the last time column (symmetric pad (K-1)*d puts the
// k=1 tap of every dilated conv in the zero pad at the final position).
// 3-kernel pipeline (proven 98.5us baseline structure minus one boundary):
//   K1: grid(41,2): 80 fold blocks (32x32x32 matmul -> fp16 blob) + prep
//       block (start conv -> c0, zero F_H/cnt).
//   K2: 8 chain blocks (1 wave, 40-layer recurrence, in-register shfl
//       all-gather z broadcast) + 128 XCD-aware L2-warmer blocks: each
//       bi&7 group (16 blocks) covers the ENTIRE tail weight set, so every
//       XCD's private L2 holds skip_w/end1_w before K3 (R5 post-mortem:
//       1/8-coverage warming = 1/8 hit rate = neutral).
//   K3: fused skip matvec + end tail via last-block election (NOT a spin;
//       same atomic-cnt pattern k3b already used): 320 blocks do the skip
//       matvec + atomicAdd into F_H; the 40th arrival per batch runs
//       end1+end2 itself and writes out[b]. Saves one ~2.5us boundary.
// R1/R4 lesson: the tail is a cold-HBM stream; width (MLP) sets its time.
// R2/R3 lesson: no fences/volatile/spin in pipelined loops.
// Algebraic fold: c_{l+1} = (Wr_l+I) z_l  =>  M_{f,g}[l] = W_{f,g}[l](Wr_{l-1}+I),
// so the serial chain is z' = tanh(M_f z) * sigmoid(M_g z).

#define NL 40
#define TLEN 8192

// ws float-offset layout
#define F_BLOB 0        // fp16 [40][64 lanes][32 halfs] = 81920 halfs
#define F_C0   40960    // [8][32]
#define F_Z    41216    // [40][8][32] fp32 z for the skip matvec
#define F_H    51456    // [8][256] skip accumulator
#define F_OB   53504    // [8] (unused, kept zeroed)
#define F_CNT  53512    // [8] ints
#define F_DUMP 60000    // DCE-proof dump for warmer blocks

typedef __attribute__((ext_vector_type(2))) _Float16 h2;

#if defined(__has_builtin)
#if __has_builtin(__builtin_amdgcn_fdot2)
#define HAS_FDOT2 1
#endif
#endif

__device__ __forceinline__ float FDOT2(h2 a, h2 b, float c) {
#ifdef HAS_FDOT2
    return __builtin_amdgcn_fdot2(a, b, c, false);
#else
    return c + (float)a.x * (float)b.x + (float)a.y * (float)b.y;
#endif
}

__device__ __forceinline__ float tanh_fast(float f) {
    f = fminf(fmaxf(f, -15.f), 15.f);
    float e2 = __expf(2.f * f);
    return (e2 - 1.f) / (e2 + 1.f);
}

// ------------------------------------------------- K1: fold weights + prep
__global__ __launch_bounds__(256) void k1_fold(
    const float* __restrict__ x, const float* __restrict__ start_w,
    const float* __restrict__ filter_w, const float* __restrict__ gate_w,
    const float* __restrict__ res_w, float* __restrict__ ws)
{
    const int l = blockIdx.x, m = blockIdx.y;   // m: 0=filter, 1=gate
    const int t = threadIdx.x;

    if (l == NL) {
        if (m == 0) {
            const int b = t >> 5, ch = t & 31;
            float acc = 0.f;
#pragma unroll
            for (int j = 0; j < 6; ++j)
                acc += start_w[ch * 6 + j] * x[(b * 6 + j) * TLEN + TLEN - 1];
            ws[F_C0 + t] = acc;
            if (t < 8) { ws[F_OB + t] = 0.f; ((int*)(ws + F_CNT))[t] = 0; }
        } else {
            for (int k = t; k < 2048; k += 256) ws[F_H + k] = 0.f;
        }
        return;
    }

    __shared__ float F[32][32];
    __shared__ __align__(16) float R[32][36];
    const float* src = m ? gate_w : filter_w;
    for (int e = t; e < 1024; e += 256)
        F[e >> 5][e & 31] = src[(l * 1024 + e) * 2];   // k=0 taps
    if (l > 0)
        for (int e = t; e < 1024; e += 256) {
            const int k = e >> 5, j = e & 31;
            R[k][j] = res_w[(l - 1) * 1024 + e] + (k == j ? 1.f : 0.f);
        }
    __syncthreads();

    const int ch = t >> 3, jg = t & 7, j0 = jg * 4;
    float o0, o1, o2, o3;
    if (l == 0) {
        o0 = F[ch][j0]; o1 = F[ch][j0+1]; o2 = F[ch][j0+2]; o3 = F[ch][j0+3];
    } else {
        o0 = o1 = o2 = o3 = 0.f;
#pragma unroll
        for (int k = 0; k < 32; ++k) {
            const float fv = F[ch][k];
            const float4 rv = *(const float4*)&R[k][j0];
            o0 += fv * rv.x; o1 += fv * rv.y; o2 += fv * rv.z; o3 += fv * rv.w;
        }
    }
    // blob: [l][lane=h*32+ch][ f:0..15 | g:16..31 ], pos = j0 & 15
    const int hh = jg >> 2;
    __half* dst = (__half*)ws + (size_t)l * 2048 + (hh * 32 + ch) * 32
                + (m ? 16 : 0) + (j0 & 15);
    ((__half2*)dst)[0] = __floats2half2_rn(o0, o1);
    ((__half2*)dst)[1] = __floats2half2_rn(o2, o3);
}

// ------------------------------------------------------------ K2: recurrence
// Chain blocks (blockIdx < 8): 1 wave, 40-layer recurrence, in-register
// z broadcast. Warmer blocks (blockIdx >= 8): XCD-grouped full-coverage
// streaming of the tail weights into each XCD's private L2.
#define K2_PREF(L, W) do {                                                   \
    if ((L) < NL) {                                                          \
        _Pragma("unroll")                                                    \
        for (int i = 0; i < 4; ++i)                                          \
            W[i] = blob[(L) * 256 + lane * 4 + i];                           \
    }                                                                        \
} while (0)

#define K2_STEP(L, W) do {                                                   \
    /* pack (z[2q], z[2q+1]) on every lane (RN, same as __float2half) */     \
    float zx = __shfl_xor(z, 1, 64);                                         \
    float ze = (ch & 1) ? zx : z;                                            \
    float zo = (ch & 1) ? z  : zx;                                           \
    __half2 pk = __halves2half2(__float2half(ze), __float2half(zo));         \
    int pki; __builtin_memcpy(&pki, &pk, 4);                                 \
    h2 sv[8];                                                                \
    _Pragma("unroll")                                                        \
    for (int i = 0; i < 8; ++i) {                                            \
        int q = __shfl(pki, hbase + 2 * i, 64);                              \
        __builtin_memcpy(&sv[i], &q, 4);                                     \
    }                                                                        \
    float f = 0.f, g = 0.f;                                                  \
    const h2* wf = (const h2*)&W[0];                                         \
    const h2* wg = (const h2*)&W[2];                                         \
    _Pragma("unroll")                                                        \
    for (int i = 0; i < 8; ++i) {                                            \
        f = FDOT2(wf[i], sv[i], f);                                          \
        g = FDOT2(wg[i], sv[i], g);                                          \
    }                                                                        \
    f += __shfl_xor(f, 32, 64);                                              \
    g += __shfl_xor(g, 32, 64);                                              \
    z = tanh_fast(f) * (1.f / (1.f + __expf(-g)));                           \
    if (h == 0) zbuf[((L) * 8 + b) * 32 + ch] = z;                           \
    K2_PREF((L) + 4, W);                                                     \
} while (0)

__global__ __launch_bounds__(256) void k2_recur(
    const float* __restrict__ skip_w, const float* __restrict__ end1_w,
    const float* __restrict__ end1_b, const float* __restrict__ end2_w,
    float* __restrict__ ws)
{
    const int bi = blockIdx.x, t = threadIdx.x;

    if (bi >= 8) {
        // ---- XCD-aware L2 warmers. Blocks with the same bi&7 land on the
        // same XCD (round-robin dispatch); each such 16-block group covers
        // the ENTIRE tail weight set so that XCD's L2 holds all of it.
        const int g  = bi & 7;
        const int wg = (bi - 8) >> 3;               // 0..15 within group
        const int li = wg * 256 + t;                // 0..4095
        const float4* s4 = (const float4*)skip_w;   // 81920 float4
        const float4* e4 = (const float4*)end1_w;   // 16384 float4
        float acc = 0.f;
        for (int i = li; i < 81920; i += 4096) acc += s4[i].x;   // 20 loads
        for (int i = li; i < 16384; i += 4096) acc += e4[i].x;   // 4 loads
        if (li < 64) acc += end2_w[li * 4] + end1_b[li * 4];
        if (acc == 1234.567f) ws[F_DUMP + g] = acc; // never true; defeats DCE
        return;
    }
    if (t >= 64) return;                            // chain: single wave

    const int b = bi, lane = t;
    const int ch = lane & 31, h = lane >> 5, hbase = h << 4;
    float* zbuf = ws + F_Z;
    float z = ws[F_C0 + b * 32 + ch];               // both halves load z[ch]

    const float4* blob = (const float4*)ws;
    float4 w0[4], w1[4], w2[4], w3[4];
    K2_PREF(0, w0); K2_PREF(1, w1); K2_PREF(2, w2); K2_PREF(3, w3);
    for (int l = 0; l < NL; l += 4) {
        K2_STEP(l + 0, w0);
        K2_STEP(l + 1, w1);
        K2_STEP(l + 2, w2);
        K2_STEP(l + 3, w3);
    }
}

// ----------------- K3: skip matvec + last-block-elected end1/end2 tail
__global__ __launch_bounds__(256) void k3_skipend(
    const float* __restrict__ skip_w,
    const float* __restrict__ end1_w, const float* __restrict__ end1_b,
    const float* __restrict__ end2_w, const float* __restrict__ end2_b,
    float* __restrict__ ws, float* __restrict__ out)
{
    const int l = blockIdx.x, b = blockIdx.y, t = threadIdx.x;
    __shared__ __align__(16) float zsm[32];
    __shared__ __align__(16) float hsm[256];
    __shared__ float psum[4];
    __shared__ int elect;

    // ---- skip matvec: row t of layer l for batch b
    if (t < 32) zsm[t] = ws[F_Z + (l * 8 + b) * 32 + t];
    __syncthreads();
    {
        const float4* w4 = (const float4*)(skip_w + (size_t)(l * 256 + t) * 32);
        const float4* z4 = (const float4*)zsm;
        float acc = 0.f;
#pragma unroll
        for (int i = 0; i < 8; ++i) {
            float4 wv = w4[i], zv = z4[i];
            acc += wv.x*zv.x + wv.y*zv.y + wv.z*zv.z + wv.w*zv.w;
        }
        atomicAdd(&ws[F_H + b * 256 + t], acc);
    }
    // __syncthreads drains vmcnt -> this block's atomics are done.
    __syncthreads();
    if (t == 0) {
        __threadfence();                             // release F_H adds
        int* cnt = (int*)(ws + F_CNT);
        int old = __hip_atomic_fetch_add(&cnt[b], 1, __ATOMIC_ACQ_REL,
                                         __HIP_MEMORY_SCOPE_AGENT);
        elect = (old == NL - 1);                     // 40th arrival runs tail
    }
    __syncthreads();
    if (!elect) return;

    // ---- elected block: end1 + relu + end2 for batch b (L2-warm weights)
    float hv = __hip_atomic_load((const float*)&ws[F_H + b * 256 + t],
                                 __ATOMIC_ACQUIRE, __HIP_MEMORY_SCOPE_AGENT);
    hsm[t] = fmaxf(hv, 0.f);                         // relu(skip_sum)
    __syncthreads();

    float e = 0.f;
    const float4* w1p = (const float4*)(end1_w + (size_t)t * 256);
    const float4* h4 = (const float4*)hsm;
#pragma unroll
    for (int i = 0; i < 64; ++i) {
        float4 wv = w1p[i], hv4 = h4[i];
        e += wv.x*hv4.x + wv.y*hv4.y + wv.z*hv4.z + wv.w*hv4.w;
    }
    e = fmaxf(e + end1_b[t], 0.f);
    float pe = e * end2_w[t];
#pragma unroll
    for (int off = 32; off > 0; off >>= 1)
        pe += __shfl_down(pe, off, 64);
    if ((t & 63) == 0) psum[t >> 6] = pe;
    __syncthreads();
    if (t == 0)
        out[b] = psum[0] + psum[1] + psum[2] + psum[3] + end2_b[0];
}

extern "C" void kernel_launch(void* const* d_in, const int* in_sizes, int n_in,
                              void* d_out, int out_size, void* d_ws, size_t ws_size,
                              hipStream_t stream) {
    const float* x        = (const float*)d_in[0];
    const float* start_w  = (const float*)d_in[1];
    const float* filter_w = (const float*)d_in[2];
    const float* gate_w   = (const float*)d_in[3];
    const float* res_w    = (const float*)d_in[4];
    const float* skip_w   = (const float*)d_in[5];
    const float* end1_w   = (const float*)d_in[6];
    const float* end1_b   = (const float*)d_in[7];
    const float* end2_w   = (const float*)d_in[8];
    const float* end2_b   = (const float*)d_in[9];
    float* out = (float*)d_out;
    float* ws  = (float*)d_ws;

    k1_fold   <<<dim3(NL + 1, 2), 256, 0, stream>>>(x, start_w, filter_w,
                                                    gate_w, res_w, ws);
    k2_recur  <<<136, 256, 0, stream>>>(skip_w, end1_w, end1_b, end2_w, ws);
    k3_skipend<<<dim3(NL, 8), 256, 0, stream>>>(skip_w, end1_w, end1_b,
                                                end2_w, end2_b, ws, out);
}

// Round 7
// 97.921 us; speedup vs baseline: 1.1190x; 1.1190x over previous
//
#include <hip/hip_runtime.h>
#include <hip/hip_fp16.h>
#include <math.h>

// WaveNet collapsed to the last time column (symmetric pad (K-1)*d puts the
// k=1 tap of every dilated conv in the zero pad at the final position).
// 4-kernel pipeline = the proven 98.4us structure (session best, R5):
//   K1: grid(41,2): 80 fold blocks (32x32x32 matmul -> fp16 blob) + prep
//       block (start conv -> c0, zero F_H/obuf/cnt).
//   K2: 8 chain blocks (1 wave, 40-layer recurrence, in-register shfl
//       all-gather z broadcast) + 128 XCD-aware L2 warmer blocks.
//   K3a: skip matvec, wide (40x8 blocks) -> full-machine MLP.
//   K3b: end1+end2, (4x8) blocks, register-prefetched end1 rows,
//        atomic-cnt finish.
// Measured lessons (R1-R6):
//   - Tail must be WIDE: 8-block standalone tail = 60us (R1); elected
//     single-block end1 = +11us (R6); in-block consumers = per-CU BW bound
//     (R2-R4, ~1.3MB/CU stream can never beat the 5us chain).
//   - Every boundary-elimination mechanism (volatile spin R2, fence-free
//     spin R3, barrier-phase R4, election R6) costs more than the ~2.5us
//     launch boundary it saves. Cross-block spin ruled out pre-session.
//   - No vmcnt-draining fence in any pipelined loop (R2: 51us).
// Algebraic fold: c_{l+1} = (Wr_l+I) z_l  =>  M_{f,g}[l] = W_{f,g}[l](Wr_{l-1}+I),
// so the serial chain is z' = tanh(M_f z) * sigmoid(M_g z).

#define NL 40
#define TLEN 8192

// ws float-offset layout
#define F_BLOB 0        // fp16 [40][64 lanes][32 halfs] = 81920 halfs
#define F_C0   40960    // [8][32]
#define F_Z    41216    // [40][8][32] fp32 z for the skip matvec
#define F_H    51456    // [8][256] skip accumulator
#define F_OB   53504    // [8]
#define F_CNT  53512    // [8] ints
#define F_DUMP 60000    // DCE-proof dump for warmer blocks

typedef __attribute__((ext_vector_type(2))) _Float16 h2;

#if defined(__has_builtin)
#if __has_builtin(__builtin_amdgcn_fdot2)
#define HAS_FDOT2 1
#endif
#endif

__device__ __forceinline__ float FDOT2(h2 a, h2 b, float c) {
#ifdef HAS_FDOT2
    return __builtin_amdgcn_fdot2(a, b, c, false);
#else
    return c + (float)a.x * (float)b.x + (float)a.y * (float)b.y;
#endif
}

__device__ __forceinline__ float tanh_fast(float f) {
    f = fminf(fmaxf(f, -15.f), 15.f);
    float e2 = __expf(2.f * f);
    return (e2 - 1.f) / (e2 + 1.f);
}

// ------------------------------------------------- K1: fold weights + prep
__global__ __launch_bounds__(256) void k1_fold(
    const float* __restrict__ x, const float* __restrict__ start_w,
    const float* __restrict__ filter_w, const float* __restrict__ gate_w,
    const float* __restrict__ res_w, float* __restrict__ ws)
{
    const int l = blockIdx.x, m = blockIdx.y;   // m: 0=filter, 1=gate
    const int t = threadIdx.x;

    if (l == NL) {
        if (m == 0) {
            const int b = t >> 5, ch = t & 31;
            float acc = 0.f;
#pragma unroll
            for (int j = 0; j < 6; ++j)
                acc += start_w[ch * 6 + j] * x[(b * 6 + j) * TLEN + TLEN - 1];
            ws[F_C0 + t] = acc;
            if (t < 8) { ws[F_OB + t] = 0.f; ((int*)(ws + F_CNT))[t] = 0; }
        } else {
            for (int k = t; k < 2048; k += 256) ws[F_H + k] = 0.f;
        }
        return;
    }

    __shared__ float F[32][32];
    __shared__ __align__(16) float R[32][36];
    const float* src = m ? gate_w : filter_w;
    for (int e = t; e < 1024; e += 256)
        F[e >> 5][e & 31] = src[(l * 1024 + e) * 2];   // k=0 taps
    if (l > 0)
        for (int e = t; e < 1024; e += 256) {
            const int k = e >> 5, j = e & 31;
            R[k][j] = res_w[(l - 1) * 1024 + e] + (k == j ? 1.f : 0.f);
        }
    __syncthreads();

    const int ch = t >> 3, jg = t & 7, j0 = jg * 4;
    float o0, o1, o2, o3;
    if (l == 0) {
        o0 = F[ch][j0]; o1 = F[ch][j0+1]; o2 = F[ch][j0+2]; o3 = F[ch][j0+3];
    } else {
        o0 = o1 = o2 = o3 = 0.f;
#pragma unroll
        for (int k = 0; k < 32; ++k) {
            const float fv = F[ch][k];
            const float4 rv = *(const float4*)&R[k][j0];
            o0 += fv * rv.x; o1 += fv * rv.y; o2 += fv * rv.z; o3 += fv * rv.w;
        }
    }
    // blob: [l][lane=h*32+ch][ f:0..15 | g:16..31 ], pos = j0 & 15
    const int hh = jg >> 2;
    __half* dst = (__half*)ws + (size_t)l * 2048 + (hh * 32 + ch) * 32
                + (m ? 16 : 0) + (j0 & 15);
    ((__half2*)dst)[0] = __floats2half2_rn(o0, o1);
    ((__half2*)dst)[1] = __floats2half2_rn(o2, o3);
}

// ------------------------------------------------------------ K2: recurrence
// Chain blocks (blockIdx < 8): 1 wave, 40-layer recurrence, in-register
// z broadcast (shfl all-gather, no LDS in the loop). Warmer blocks
// (blockIdx >= 8): XCD-grouped full-coverage streaming of the tail weights
// into each XCD's private L2.
#define K2_PREF(L, W) do {                                                   \
    if ((L) < NL) {                                                          \
        _Pragma("unroll")                                                    \
        for (int i = 0; i < 4; ++i)                                          \
            W[i] = blob[(L) * 256 + lane * 4 + i];                           \
    }                                                                        \
} while (0)

#define K2_STEP(L, W) do {                                                   \
    /* pack (z[2q], z[2q+1]) on every lane (RN, same as __float2half) */     \
    float zx = __shfl_xor(z, 1, 64);                                         \
    float ze = (ch & 1) ? zx : z;                                            \
    float zo = (ch & 1) ? z  : zx;                                           \
    __half2 pk = __halves2half2(__float2half(ze), __float2half(zo));         \
    int pki; __builtin_memcpy(&pki, &pk, 4);                                 \
    h2 sv[8];                                                                \
    _Pragma("unroll")                                                        \
    for (int i = 0; i < 8; ++i) {                                            \
        int q = __shfl(pki, hbase + 2 * i, 64);                              \
        __builtin_memcpy(&sv[i], &q, 4);                                     \
    }                                                                        \
    float f = 0.f, g = 0.f;                                                  \
    const h2* wf = (const h2*)&W[0];                                         \
    const h2* wg = (const h2*)&W[2];                                         \
    _Pragma("unroll")                                                        \
    for (int i = 0; i < 8; ++i) {                                            \
        f = FDOT2(wf[i], sv[i], f);                                          \
        g = FDOT2(wg[i], sv[i], g);                                          \
    }                                                                        \
    f += __shfl_xor(f, 32, 64);                                              \
    g += __shfl_xor(g, 32, 64);                                              \
    z = tanh_fast(f) * (1.f / (1.f + __expf(-g)));                           \
    if (h == 0) zbuf[((L) * 8 + b) * 32 + ch] = z;                           \
    K2_PREF((L) + 4, W);                                                     \
} while (0)

__global__ __launch_bounds__(256) void k2_recur(
    const float* __restrict__ skip_w, const float* __restrict__ end1_w,
    const float* __restrict__ end1_b, const float* __restrict__ end2_w,
    float* __restrict__ ws)
{
    const int bi = blockIdx.x, t = threadIdx.x;

    if (bi >= 8) {
        // ---- XCD-aware L2 warmers. Blocks with the same bi&7 land on the
        // same XCD (round-robin dispatch); each such 16-block group covers
        // the ENTIRE tail weight set so that XCD's L2 holds all of it.
        const int g  = bi & 7;
        const int wg = (bi - 8) >> 3;               // 0..15 within group
        const int li = wg * 256 + t;                // 0..4095
        const float4* s4 = (const float4*)skip_w;   // 81920 float4
        const float4* e4 = (const float4*)end1_w;   // 16384 float4
        float acc = 0.f;
        for (int i = li; i < 81920; i += 4096) acc += s4[i].x;   // 20 loads
        for (int i = li; i < 16384; i += 4096) acc += e4[i].x;   // 4 loads
        if (li < 64) acc += end2_w[li * 4] + end1_b[li * 4];
        if (acc == 1234.567f) ws[F_DUMP + g] = acc; // never true; defeats DCE
        return;
    }
    if (t >= 64) return;                            // chain: single wave

    const int b = bi, lane = t;
    const int ch = lane & 31, h = lane >> 5, hbase = h << 4;
    float* zbuf = ws + F_Z;
    float z = ws[F_C0 + b * 32 + ch];               // both halves load z[ch]

    const float4* blob = (const float4*)ws;
    float4 w0[4], w1[4], w2[4], w3[4];
    K2_PREF(0, w0); K2_PREF(1, w1); K2_PREF(2, w2); K2_PREF(3, w3);
    for (int l = 0; l < NL; l += 4) {
        K2_STEP(l + 0, w0);
        K2_STEP(l + 1, w1);
        K2_STEP(l + 2, w2);
        K2_STEP(l + 3, w3);
    }
}

// ------------------------------------------------------- K3a: skip matvec
__global__ __launch_bounds__(256) void k3a_skip(
    const float* __restrict__ skip_w, float* __restrict__ ws)
{
    const int l = blockIdx.x, b = blockIdx.y, t = threadIdx.x;
    __shared__ __align__(16) float zsm[32];
    if (t < 32) zsm[t] = ws[F_Z + (l * 8 + b) * 32 + t];
    __syncthreads();
    const float4* w4 = (const float4*)(skip_w + (size_t)(l * 256 + t) * 32);
    const float4* z4 = (const float4*)zsm;
    float acc = 0.f;
#pragma unroll
    for (int i = 0; i < 8; ++i) {
        float4 wv = w4[i], zv = z4[i];
        acc += wv.x*zv.x + wv.y*zv.y + wv.z*zv.z + wv.w*zv.w;
    }
    atomicAdd(&ws[F_H + b * 256 + t], acc);
}

// --------------------------------------------------- K3b: end1 + end2 + out
__global__ __launch_bounds__(256) void k3b_end(
    const float* __restrict__ end1_w, const float* __restrict__ end1_b,
    const float* __restrict__ end2_w, const float* __restrict__ end2_b,
    float* __restrict__ ws, float* __restrict__ out)
{
    const int q = blockIdx.x, b = blockIdx.y, t = threadIdx.x;
    __shared__ __align__(16) float hsm[256];
    __shared__ float psum[64][5];
    const int p = t >> 6, oc = t & 63, row = q * 64 + oc;

    float4 wreg[16];
    const float4* wp = (const float4*)(end1_w + (size_t)row * 256 + p * 64);
#pragma unroll
    for (int i = 0; i < 16; ++i) wreg[i] = wp[i];

    hsm[t] = fmaxf(ws[F_H + b * 256 + t], 0.f);   // relu(skip_sum)
    __syncthreads();
    const float4* h4 = (const float4*)(hsm + p * 64);
    float acc = 0.f;
#pragma unroll
    for (int i = 0; i < 16; ++i) {
        float4 wv = wreg[i], hv = h4[i];
        acc += wv.x*hv.x + wv.y*hv.y + wv.z*hv.z + wv.w*hv.w;
    }
    psum[oc][p] = acc;
    __syncthreads();
    if (t < 64) {
        const int rr = q * 64 + t;
        float e = psum[t][0] + psum[t][1] + psum[t][2] + psum[t][3]
                + end1_b[rr];
        e = fmaxf(e, 0.f);
        float pe = e * end2_w[rr];
#pragma unroll
        for (int off = 32; off > 0; off >>= 1)
            pe += __shfl_down(pe, off, 64);
        if (t == 0) {
            float* obuf = ws + F_OB;
            int* cnt = (int*)(ws + F_CNT);
            atomicAdd(&obuf[b], pe);
            __threadfence();
            int old = __hip_atomic_fetch_add(&cnt[b], 1, __ATOMIC_ACQ_REL,
                                             __HIP_MEMORY_SCOPE_AGENT);
            if (old == 3) {
                float tot = __hip_atomic_load(&obuf[b], __ATOMIC_ACQUIRE,
                                              __HIP_MEMORY_SCOPE_AGENT);
                out[b] = tot + end2_b[0];
            }
        }
    }
}

extern "C" void kernel_launch(void* const* d_in, const int* in_sizes, int n_in,
                              void* d_out, int out_size, void* d_ws, size_t ws_size,
                              hipStream_t stream) {
    const float* x        = (const float*)d_in[0];
    const float* start_w  = (const float*)d_in[1];
    const float* filter_w = (const float*)d_in[2];
    const float* gate_w   = (const float*)d_in[3];
    const float* res_w    = (const float*)d_in[4];
    const float* skip_w   = (const float*)d_in[5];
    const float* end1_w   = (const float*)d_in[6];
    const float* end1_b   = (const float*)d_in[7];
    const float* end2_w   = (const float*)d_in[8];
    const float* end2_b   = (const float*)d_in[9];
    float* out = (float*)d_out;
    float* ws  = (float*)d_ws;

    k1_fold <<<dim3(NL + 1, 2), 256, 0, stream>>>(x, start_w, filter_w,
                                                  gate_w, res_w, ws);
    k2_recur<<<136, 256, 0, stream>>>(skip_w, end1_w, end1_b, end2_w, ws);
    k3a_skip<<<dim3(NL, 8), 256, 0, stream>>>(skip_w, ws);
    k3b_end <<<dim3(4, 8), 256, 0, stream>>>(end1_w, end1_b, end2_w, end2_b,
                                             ws, out);
}